// Round 3
// baseline (1416.985 us; speedup 1.0000x reference)
//
#include <hip/hip_runtime.h>

// ---------------------------------------------------------------------------
// MultiviewSNF: 3x (x@w1 -> spmm -> +b,relu -> @w2 -> spmm -> +b) -> fusion -> q
// N=50000 nodes, E=800000 edges/view, HID=128, EMB=64, K=10
// Round 3: gemm1 64-row tiles + BK=64 + register-prefetch pipeline (occupancy
// 16%->~40%, latency hidden); batched CSR build across views; spmm unroll 8.
// ---------------------------------------------------------------------------

#define N_NODES 50000
#define N_EDGES 800000
#define HID 128
#define EMB 64
#define NCLU 10

using bf16x8 = __attribute__((ext_vector_type(8))) short;
using f32x4  = __attribute__((ext_vector_type(4))) float;

static __device__ __forceinline__ unsigned short f2bf(float f) {
    unsigned int u = __float_as_uint(f);
    unsigned int r = (u + 0x7FFF + ((u >> 16) & 1)) >> 16;  // RNE
    return (unsigned short)r;
}
static __device__ __forceinline__ float bflo(unsigned int t) {
    return __uint_as_float(t << 16);
}
static __device__ __forceinline__ float bfhi(unsigned int t) {
    return __uint_as_float(t & 0xFFFF0000u);
}

// ---------------- CSR build (batched over 3 views) ----------------

__global__ void hist3_kernel(const int* __restrict__ r0, const int* __restrict__ r1,
                             const int* __restrict__ r2, int* __restrict__ counts) {
    int t = blockIdx.x * 256 + threadIdx.x;          // 0..3E
    int view = t / N_EDGES;
    int i = t - view * N_EDGES;
    const int* rp = (view == 0) ? r0 : (view == 1) ? r1 : r2;
    atomicAdd(&counts[view * N_NODES + rp[i]], 1);
}

// block-local exclusive scan of 256 counts
__global__ __launch_bounds__(256) void scan1_kernel(
    const int* __restrict__ counts, int* __restrict__ tmp, int* __restrict__ bsum, int n)
{
    __shared__ int wt[4];
    int t = threadIdx.x, b = blockIdx.x;
    int i = b * 256 + t;
    int lane = t & 63, wid = t >> 6;
    int v = (i < n) ? counts[i] : 0;
    int incl = v;
    #pragma unroll
    for (int d = 1; d < 64; d <<= 1) {
        int u = __shfl_up(incl, d, 64);
        if (lane >= d) incl += u;
    }
    if (lane == 63) wt[wid] = incl;
    __syncthreads();
    int woff = 0;
    #pragma unroll
    for (int w = 0; w < 4; ++w) if (w < wid) woff += wt[w];
    if (i < n) tmp[i] = woff + incl - v;
    if (t == 255) bsum[b] = woff + incl;
}

// single block: exclusive scan of nb block sums (nb may exceed 256); row_ptr[n]=total
__global__ __launch_bounds__(256) void scan2_kernel(
    const int* __restrict__ bsum, int* __restrict__ boff, int nb,
    int* __restrict__ row_ptr, int n)
{
    __shared__ int wt[4];
    int t = threadIdx.x;
    int lane = t & 63, wid = t >> 6;
    int carry = 0;
    for (int c0 = 0; c0 < nb; c0 += 256) {
        int i = c0 + t;
        int v = (i < nb) ? bsum[i] : 0;
        int incl = v;
        #pragma unroll
        for (int d = 1; d < 64; d <<= 1) {
            int u = __shfl_up(incl, d, 64);
            if (lane >= d) incl += u;
        }
        __syncthreads();  // protect wt from previous chunk's readers
        if (lane == 63) wt[wid] = incl;
        __syncthreads();
        int woff = 0;
        #pragma unroll
        for (int w = 0; w < 4; ++w) if (w < wid) woff += wt[w];
        int chunktot = wt[0] + wt[1] + wt[2] + wt[3];
        if (i < nb) boff[i] = carry + woff + incl - v;
        carry += chunktot;  // uniform across threads
    }
    if (t == 0) row_ptr[n] = carry;
}

__global__ __launch_bounds__(256) void scan3_kernel(
    const int* __restrict__ tmp, const int* __restrict__ boff,
    int* __restrict__ row_ptr, int* __restrict__ cursor, int n)
{
    int i = blockIdx.x * 256 + threadIdx.x;
    if (i < n) {
        int e = tmp[i] + boff[blockIdx.x];
        row_ptr[i] = e;
        cursor[i] = e;
    }
}

// scatter all 3 views into CSR order as packed (col:int-bits, val:float) pairs
__global__ void scatter3_kernel(
    const int* __restrict__ r0, const int* __restrict__ c0, const float* __restrict__ v0,
    const int* __restrict__ r1, const int* __restrict__ c1, const float* __restrict__ v1,
    const int* __restrict__ r2, const int* __restrict__ c2, const float* __restrict__ v2,
    int* __restrict__ cursor, float2* __restrict__ cv)
{
    int t = blockIdx.x * 256 + threadIdx.x;  // 0..3E
    int view = t / N_EDGES;
    int i = t - view * N_EDGES;
    const int* rp = (view == 0) ? r0 : (view == 1) ? r1 : r2;
    const int* cp = (view == 0) ? c0 : (view == 1) ? c1 : c2;
    const float* vp = (view == 0) ? v0 : (view == 1) ? v1 : v2;
    int r = view * N_NODES + rp[i];
    int p = atomicAdd(&cursor[r], 1);
    float2 e;
    e.x = __uint_as_float((unsigned int)cp[i]);
    e.y = vp[i];
    cv[p] = e;
}

// ---------------- weight convert: w1[din][128] fp32 -> w1t[128][dinp] bf16 ----------------

__global__ void wconv_kernel(const float* __restrict__ w, unsigned short* __restrict__ wt,
                             int din, int dinp) {
    int t = blockIdx.x * 256 + threadIdx.x;
    if (t >= 128 * dinp) return;
    int n = t / dinp, k = t - n * dinp;
    float f = (k < din) ? w[(size_t)k * 128 + n] : 0.f;
    wt[(size_t)n * dinp + k] = f2bf(f);
}

// ---------------- GEMM1: xw[N][128] (bf16) = x[N][din] @ w1 (bf16 MFMA) ----------------
// 64x128 tile, 4 waves (each 64 rows x 32 cols), BK=64, register-prefetch pipeline.

#define SAW 72  // LDS row stride (shorts): 144B = 9*16B -> 16B aligned, <=2-way bank alias

__global__ __launch_bounds__(256) void gemm1_kernel(
    const float* __restrict__ x, const unsigned short* __restrict__ w1t,
    unsigned short* __restrict__ xw, int Nn, int din, int dinp)
{
    __shared__ unsigned short As[64 * SAW];
    __shared__ unsigned short Bs[128 * SAW];
    int tid = threadIdx.x;
    int lane = tid & 63, wid = tid >> 6;
    int row0 = blockIdx.x * 64;
    int numK = dinp >> 6;

    int ar = tid >> 4;         // 0..15 (A stage row within pass)
    int ak = (tid & 15) * 4;   // 0..60 (A stage k)
    float4 apre[4];
    uint4  bpre[4];

    auto loadA = [&](int k0) {
        #pragma unroll
        for (int p = 0; p < 4; ++p) {
            int r = p * 16 + ar;
            int gr = row0 + r;
            int k = k0 + ak;
            float4 v = make_float4(0.f, 0.f, 0.f, 0.f);
            if (gr < Nn) {
                if (k + 4 <= din) {
                    v = *(const float4*)(x + (size_t)gr * din + k);
                } else {
                    float e0 = (k + 0 < din) ? x[(size_t)gr * din + k + 0] : 0.f;
                    float e1 = (k + 1 < din) ? x[(size_t)gr * din + k + 1] : 0.f;
                    float e2 = (k + 2 < din) ? x[(size_t)gr * din + k + 2] : 0.f;
                    float e3 = (k + 3 < din) ? x[(size_t)gr * din + k + 3] : 0.f;
                    v = make_float4(e0, e1, e2, e3);
                }
            }
            apre[p] = v;
        }
    };
    auto loadB = [&](int k0) {
        #pragma unroll
        for (int p = 0; p < 4; ++p) {
            int idx = p * 256 + tid;
            int n = idx >> 3, q = idx & 7;
            bpre[p] = *(const uint4*)(w1t + (size_t)n * dinp + k0 + q * 8);
        }
    };
    auto storeLDS = [&]() {
        #pragma unroll
        for (int p = 0; p < 4; ++p) {
            int r = p * 16 + ar;
            ushort4 b;
            b.x = f2bf(apre[p].x); b.y = f2bf(apre[p].y);
            b.z = f2bf(apre[p].z); b.w = f2bf(apre[p].w);
            *(ushort4*)(&As[r * SAW + ak]) = b;
        }
        #pragma unroll
        for (int p = 0; p < 4; ++p) {
            int idx = p * 256 + tid;
            int n = idx >> 3, q = idx & 7;
            *(uint4*)(&Bs[n * SAW + q * 8]) = bpre[p];
        }
    };

    loadA(0); loadB(0);
    storeLDS();

    int kq = (lane >> 4) * 8;
    int sub = lane & 15;
    f32x4 acc[4][2] = {};
    for (int kt = 0;;) {
        __syncthreads();
        bool more = (kt + 1 < numK);
        if (more) { loadA((kt + 1) << 6); loadB((kt + 1) << 6); }
        #pragma unroll
        for (int kh = 0; kh < 2; ++kh) {
            bf16x8 af[4], bfr[2];
            #pragma unroll
            for (int mt = 0; mt < 4; ++mt)
                af[mt] = *(const bf16x8*)(&As[(mt * 16 + sub) * SAW + kh * 32 + kq]);
            #pragma unroll
            for (int nt = 0; nt < 2; ++nt)
                bfr[nt] = *(const bf16x8*)(&Bs[(wid * 32 + nt * 16 + sub) * SAW + kh * 32 + kq]);
            #pragma unroll
            for (int mt = 0; mt < 4; ++mt)
                #pragma unroll
                for (int nt = 0; nt < 2; ++nt)
                    acc[mt][nt] = __builtin_amdgcn_mfma_f32_16x16x32_bf16(af[mt], bfr[nt], acc[mt][nt], 0, 0, 0);
        }
        if (!more) break;
        __syncthreads();
        storeLDS();  // vmcnt drain for prefetch happens here, after MFMAs
        ++kt;
    }

    // C layout: col = lane&15, row = (lane>>4)*4 + reg
    #pragma unroll
    for (int mt = 0; mt < 4; ++mt) {
        #pragma unroll
        for (int nt = 0; nt < 2; ++nt) {
            int col = wid * 32 + nt * 16 + (lane & 15);
            #pragma unroll
            for (int r = 0; r < 4; ++r) {
                int row = row0 + mt * 16 + (lane >> 4) * 4 + r;
                if (row < Nn) xw[(size_t)row * 128 + col] = f2bf(acc[mt][nt][r]);
            }
        }
    }
}

// ---------------- SpMM F=128 (bf16 src), bias+relu, bf16 dst ----------------

__global__ __launch_bounds__(256) void spmm128_kernel(
    const unsigned short* __restrict__ src, const int* __restrict__ row_ptr,
    const float2* __restrict__ cv, const float* __restrict__ bias,
    unsigned short* __restrict__ dst)
{
    const unsigned int* srcu = (const unsigned int*)src;
    int lane = threadIdx.x & 63;
    int r = blockIdx.x * 4 + (threadIdx.x >> 6);
    int s = row_ptr[r], e = row_ptr[r + 1];
    float a0 = 0.f, a1 = 0.f, b0 = 0.f, b1 = 0.f;
    int j = s;
    for (; j + 8 <= e; j += 8) {
        float2 p0 = cv[j], p1 = cv[j + 1], p2 = cv[j + 2], p3 = cv[j + 3];
        float2 p4 = cv[j + 4], p5 = cv[j + 5], p6 = cv[j + 6], p7 = cv[j + 7];
        unsigned int t0 = srcu[(size_t)__float_as_uint(p0.x) * 64 + lane];
        unsigned int t1 = srcu[(size_t)__float_as_uint(p1.x) * 64 + lane];
        unsigned int t2 = srcu[(size_t)__float_as_uint(p2.x) * 64 + lane];
        unsigned int t3 = srcu[(size_t)__float_as_uint(p3.x) * 64 + lane];
        unsigned int t4 = srcu[(size_t)__float_as_uint(p4.x) * 64 + lane];
        unsigned int t5 = srcu[(size_t)__float_as_uint(p5.x) * 64 + lane];
        unsigned int t6 = srcu[(size_t)__float_as_uint(p6.x) * 64 + lane];
        unsigned int t7 = srcu[(size_t)__float_as_uint(p7.x) * 64 + lane];
        a0 += p0.y * bflo(t0); a1 += p0.y * bfhi(t0);
        b0 += p1.y * bflo(t1); b1 += p1.y * bfhi(t1);
        a0 += p2.y * bflo(t2); a1 += p2.y * bfhi(t2);
        b0 += p3.y * bflo(t3); b1 += p3.y * bfhi(t3);
        a0 += p4.y * bflo(t4); a1 += p4.y * bfhi(t4);
        b0 += p5.y * bflo(t5); b1 += p5.y * bfhi(t5);
        a0 += p6.y * bflo(t6); a1 += p6.y * bfhi(t6);
        b0 += p7.y * bflo(t7); b1 += p7.y * bfhi(t7);
    }
    for (; j < e; ++j) {
        float2 p = cv[j];
        unsigned int t = srcu[(size_t)__float_as_uint(p.x) * 64 + lane];
        a0 += p.y * bflo(t); a1 += p.y * bfhi(t);
    }
    a0 += b0 + bias[lane * 2];
    a1 += b1 + bias[lane * 2 + 1];
    a0 = fmaxf(a0, 0.f); a1 = fmaxf(a1, 0.f);
    unsigned int o = (unsigned int)f2bf(a0) | ((unsigned int)f2bf(a1) << 16);
    ((unsigned int*)dst)[(size_t)r * 64 + lane] = o;
}

// ---------------- SpMM F=64 (bf16 src), +bias, fp32 dst ----------------

__global__ __launch_bounds__(256) void spmm64_kernel(
    const unsigned short* __restrict__ src, const int* __restrict__ row_ptr,
    const float2* __restrict__ cv, const float* __restrict__ bias,
    float* __restrict__ dst)
{
    int lane = threadIdx.x & 63;
    int r = blockIdx.x * 4 + (threadIdx.x >> 6);
    int s = row_ptr[r], e = row_ptr[r + 1];
    float a0 = 0.f, b0 = 0.f;
    int j = s;
    for (; j + 8 <= e; j += 8) {
        float2 p0 = cv[j], p1 = cv[j + 1], p2 = cv[j + 2], p3 = cv[j + 3];
        float2 p4 = cv[j + 4], p5 = cv[j + 5], p6 = cv[j + 6], p7 = cv[j + 7];
        float f0 = __uint_as_float((unsigned int)src[(size_t)__float_as_uint(p0.x) * 64 + lane] << 16);
        float f1 = __uint_as_float((unsigned int)src[(size_t)__float_as_uint(p1.x) * 64 + lane] << 16);
        float f2 = __uint_as_float((unsigned int)src[(size_t)__float_as_uint(p2.x) * 64 + lane] << 16);
        float f3 = __uint_as_float((unsigned int)src[(size_t)__float_as_uint(p3.x) * 64 + lane] << 16);
        float f4 = __uint_as_float((unsigned int)src[(size_t)__float_as_uint(p4.x) * 64 + lane] << 16);
        float f5 = __uint_as_float((unsigned int)src[(size_t)__float_as_uint(p5.x) * 64 + lane] << 16);
        float f6 = __uint_as_float((unsigned int)src[(size_t)__float_as_uint(p6.x) * 64 + lane] << 16);
        float f7 = __uint_as_float((unsigned int)src[(size_t)__float_as_uint(p7.x) * 64 + lane] << 16);
        a0 += p0.y * f0; b0 += p1.y * f1;
        a0 += p2.y * f2; b0 += p3.y * f3;
        a0 += p4.y * f4; b0 += p5.y * f5;
        a0 += p6.y * f6; b0 += p7.y * f7;
    }
    for (; j < e; ++j) {
        float2 p = cv[j];
        float f = __uint_as_float((unsigned int)src[(size_t)__float_as_uint(p.x) * 64 + lane] << 16);
        a0 += p.y * f;
    }
    dst[(size_t)r * 64 + lane] = a0 + b0 + bias[lane];
}

// ---------------- GEMM2: hw[N][64] (bf16) = h[N][128] (bf16) @ w2[128][64] (fp32 LDS) ----

__global__ __launch_bounds__(256) void gemm2_kernel(
    const unsigned short* __restrict__ h, const float* __restrict__ w2,
    unsigned short* __restrict__ hw)
{
    __shared__ float w2s[128 * 64];
    int tid = threadIdx.x;
    for (int i = tid; i < 128 * 64; i += 256) w2s[i] = w2[i];
    __syncthreads();
    int n = tid & 63, g = tid >> 6;
    int r0 = blockIdx.x * 16 + g * 4;
    const unsigned int* h0 = (const unsigned int*)(h + (size_t)r0 * 128);
    float a0 = 0.f, a1 = 0.f, a2 = 0.f, a3 = 0.f;
    #pragma unroll 4
    for (int k2 = 0; k2 < 64; ++k2) {
        unsigned int t0 = h0[k2], t1 = h0[64 + k2], t2 = h0[128 + k2], t3 = h0[192 + k2];
        float w0 = w2s[(2 * k2) * 64 + n];
        float w1 = w2s[(2 * k2 + 1) * 64 + n];
        a0 += bflo(t0) * w0 + bfhi(t0) * w1;
        a1 += bflo(t1) * w0 + bfhi(t1) * w1;
        a2 += bflo(t2) * w0 + bfhi(t2) * w1;
        a3 += bflo(t3) * w0 + bfhi(t3) * w1;
    }
    hw[(size_t)(r0 + 0) * 64 + n] = f2bf(a0);
    hw[(size_t)(r0 + 1) * 64 + n] = f2bf(a1);
    hw[(size_t)(r0 + 2) * 64 + n] = f2bf(a2);
    hw[(size_t)(r0 + 3) * 64 + n] = f2bf(a3);
}

// ---------------- fusion: z_fused = relu(concat(z0,z1,z2) @ fw + fb) ----------------

__global__ __launch_bounds__(256) void fusion_kernel(
    const float* __restrict__ z, const float* __restrict__ fw,
    const float* __restrict__ fb, float* __restrict__ zf)
{
    __shared__ float ws_[192 * 64];  // 48 KB
    int tid = threadIdx.x;
    for (int i = tid; i < 192 * 64; i += 256) ws_[i] = fw[i];
    __syncthreads();
    int n = tid & 63, g = tid >> 6;
    int r0 = blockIdx.x * 16 + g * 4;
    float a0 = 0.f, a1 = 0.f, a2 = 0.f, a3 = 0.f;
    #pragma unroll
    for (int v = 0; v < 3; ++v) {
        const float* zv = z + (size_t)v * N_NODES * 64;
        const float* z0 = zv + (size_t)(r0 + 0) * 64;
        const float* z1 = zv + (size_t)(r0 + 1) * 64;
        const float* z2 = zv + (size_t)(r0 + 2) * 64;
        const float* z3 = zv + (size_t)(r0 + 3) * 64;
        #pragma unroll 4
        for (int k = 0; k < 64; ++k) {
            float w = ws_[(v * 64 + k) * 64 + n];
            a0 += z0[k] * w; a1 += z1[k] * w; a2 += z2[k] * w; a3 += z3[k] * w;
        }
    }
    float b = fb[n];
    zf[(size_t)(r0 + 0) * 64 + n] = fmaxf(a0 + b, 0.f);
    zf[(size_t)(r0 + 1) * 64 + n] = fmaxf(a1 + b, 0.f);
    zf[(size_t)(r0 + 2) * 64 + n] = fmaxf(a2 + b, 0.f);
    zf[(size_t)(r0 + 3) * 64 + n] = fmaxf(a3 + b, 0.f);
}

// ---------------- q: Student-t soft assignment ----------------

__global__ __launch_bounds__(256) void q_kernel(
    const float* __restrict__ zf, const float* __restrict__ cluster, float* __restrict__ q)
{
    int lane = threadIdx.x & 63;
    int r = blockIdx.x * 4 + (threadIdx.x >> 6);
    float zl = zf[(size_t)r * 64 + lane];
    float d2[NCLU];
    #pragma unroll
    for (int k = 0; k < NCLU; ++k) {
        float d = zl - cluster[k * 64 + lane];
        float s = d * d;
        #pragma unroll
        for (int m = 32; m; m >>= 1) s += __shfl_xor(s, m, 64);
        d2[k] = s;
    }
    float S = 0.f;
    #pragma unroll
    for (int k = 0; k < NCLU; ++k) S += 1.f / (1.f + d2[k]);
    float myq = 0.f;
    #pragma unroll
    for (int k = 0; k < NCLU; ++k)
        if (lane == k) myq = 1.f / (1.f + d2[k]);
    if (lane < NCLU) q[(size_t)r * NCLU + lane] = myq / S;
}

// ---------------- launch ----------------

extern "C" void kernel_launch(void* const* d_in, const int* in_sizes, int n_in,
                              void* d_out, int out_size, void* d_ws, size_t ws_size,
                              hipStream_t stream)
{
    const int N = N_NODES, E = N_EDGES;
    const int N3 = 3 * N, E3 = 3 * E;
    const int NB3 = (N3 + 255) / 256;  // 586 scan blocks
    static const int dins[3] = {1000, 800, 600};
    float* out = (float*)d_out;
    char* base = (char*)d_ws;
    size_t off = 0;
    auto alloc = [&](size_t bytes) -> void* {
        void* p = base + off;
        off = (off + bytes + 255) & ~(size_t)255;
        return p;
    };
    unsigned short* xw = (unsigned short*)alloc((size_t)N * 128 * 2);
    unsigned short* h  = (unsigned short*)alloc((size_t)N * 128 * 2);
    unsigned short* hw = (unsigned short*)alloc((size_t)N * 64 * 2);
    unsigned short* w1t = (unsigned short*)alloc(128 * 1024 * 2);
    int* counts  = (int*)alloc((size_t)N3 * 4);
    int* cursor  = (int*)alloc((size_t)N3 * 4);
    int* row_ptr = (int*)alloc((size_t)(N3 + 1) * 4);
    int* tmp     = (int*)alloc((size_t)N3 * 4);
    int* bsum    = (int*)alloc((size_t)NB3 * 4);
    int* boff    = (int*)alloc((size_t)NB3 * 4);
    float2* cv   = (float2*)alloc((size_t)E3 * 8);

    const int* rows0 = (const int*)d_in[1];
    const int* cols0 = (const int*)d_in[2];
    const float* vals0 = (const float*)d_in[3];
    const int* rows1 = (const int*)d_in[9];
    const int* cols1 = (const int*)d_in[10];
    const float* vals1 = (const float*)d_in[11];
    const int* rows2 = (const int*)d_in[17];
    const int* cols2 = (const int*)d_in[18];
    const float* vals2 = (const float*)d_in[19];

    // batched CSR build over all 3 views
    hipMemsetAsync(counts, 0, (size_t)N3 * 4, stream);
    hist3_kernel<<<E3 / 256, 256, 0, stream>>>(rows0, rows1, rows2, counts);
    scan1_kernel<<<NB3, 256, 0, stream>>>(counts, tmp, bsum, N3);
    scan2_kernel<<<1, 256, 0, stream>>>(bsum, boff, NB3, row_ptr, N3);
    scan3_kernel<<<NB3, 256, 0, stream>>>(tmp, boff, row_ptr, cursor, N3);
    scatter3_kernel<<<E3 / 256, 256, 0, stream>>>(rows0, cols0, vals0,
                                                  rows1, cols1, vals1,
                                                  rows2, cols2, vals2, cursor, cv);

    for (int v = 0; v < 3; ++v) {
        const float* x    = (const float*)d_in[8 * v + 0];
        const float* w1   = (const float*)d_in[8 * v + 4];
        const float* b1   = (const float*)d_in[8 * v + 5];
        const float* w2   = (const float*)d_in[8 * v + 6];
        const float* b2   = (const float*)d_in[8 * v + 7];
        int din = dins[v], dinp = (din + 63) & ~63;

        wconv_kernel<<<(128 * dinp + 255) / 256, 256, 0, stream>>>(w1, w1t, din, dinp);
        gemm1_kernel<<<(N + 63) / 64, 256, 0, stream>>>(x, w1t, xw, N, din, dinp);
        spmm128_kernel<<<N / 4, 256, 0, stream>>>(xw, row_ptr + v * N, cv, b1, h);
        gemm2_kernel<<<N / 16, 256, 0, stream>>>(h, w2, hw);
        spmm64_kernel<<<N / 4, 256, 0, stream>>>(hw, row_ptr + v * N, cv, b2,
                                                 out + (size_t)v * N * 64);
    }
    const float* fw = (const float*)d_in[24];
    const float* fb = (const float*)d_in[25];
    const float* cl = (const float*)d_in[26];
    fusion_kernel<<<N / 16, 256, 0, stream>>>(out, fw, fb, out + (size_t)3 * N * 64);
    q_kernel<<<N / 4, 256, 0, stream>>>(out + (size_t)3 * N * 64, cl, out + (size_t)4 * N * 64);
}

// Round 4
// 1234.333 us; speedup vs baseline: 1.1480x; 1.1480x over previous
//
#include <hip/hip_runtime.h>

// ---------------------------------------------------------------------------
// MultiviewSNF: 3x (x@w1 -> spmm -> +b,relu -> @w2 -> spmm -> +b) -> fusion -> q
// N=50000 nodes, E=800000 edges/view, HID=128, EMB=64, K=10
// Round 4: CSR build rewritten as two-phase stable bucket sort with ONLY
// block-private scatter writes (round-3 scatter3 showed 153MB WRITE for a
// 19.2MB array = 8x cross-XCD partial-line writeback amplification).
// ---------------------------------------------------------------------------

#define N_NODES 50000
#define N_EDGES 800000
#define HID 128
#define EMB 64
#define NCLU 10

#define E3 (3 * N_EDGES)        // 2,400,000
#define N3 (3 * N_NODES)        // 150,000
#define CHK 4096                // edges per binA block
#define NBLK 586                // ceil(E3/CHK)
#define NBUK 1172               // ceil(N3/128), 128 rows per bucket
#define BUFCAP 4352             // binB LDS edge cap (mean 2048, sigma ~45)

using bf16x8 = __attribute__((ext_vector_type(8))) short;
using f32x4  = __attribute__((ext_vector_type(4))) float;

static __device__ __forceinline__ unsigned short f2bf(float f) {
    unsigned int u = __float_as_uint(f);
    unsigned int r = (u + 0x7FFF + ((u >> 16) & 1)) >> 16;  // RNE
    return (unsigned short)r;
}
static __device__ __forceinline__ float bflo(unsigned int t) {
    return __uint_as_float(t << 16);
}
static __device__ __forceinline__ float bfhi(unsigned int t) {
    return __uint_as_float(t & 0xFFFF0000u);
}
static __device__ __forceinline__ int wave_incl_scan(int v, int lane) {
    #pragma unroll
    for (int d = 1; d < 64; d <<= 1) {
        int u = __shfl_up(v, d, 64);
        if (lane >= d) v += u;
    }
    return v;
}

// ---------------- CSR build phase A: block-local bucket sort ----------------
// Each block sorts its 4096-edge chunk by bucket (row>>7) into a PRIVATE
// contiguous chunk region. Writes counts/runstart tables contiguously.

__global__ __launch_bounds__(256) void binA_kernel(
    const int* __restrict__ r0, const int* __restrict__ c0, const float* __restrict__ v0,
    const int* __restrict__ r1, const int* __restrict__ c1, const float* __restrict__ v1,
    const int* __restrict__ r2, const int* __restrict__ c2, const float* __restrict__ v2,
    int* __restrict__ runstart, int* __restrict__ counts, uint2* __restrict__ chunkout)
{
    __shared__ int hist[NBUK];
    __shared__ int wt[4];
    int tid = threadIdx.x, blk = blockIdx.x;
    int lane = tid & 63, wid = tid >> 6;
    int base = blk * CHK;
    int cnt = min(CHK, E3 - base);
    for (int i = tid; i < NBUK; i += 256) hist[i] = 0;
    __syncthreads();
    // pass 1: bucket histogram (LDS atomics)
    for (int j = tid; j < cnt; j += 256) {
        int t = base + j;
        int view = t / N_EDGES;
        int i = t - view * N_EDGES;
        const int* rp = (view == 0) ? r0 : (view == 1) ? r1 : r2;
        int grow = view * N_NODES + rp[i];
        atomicAdd(&hist[grow >> 7], 1);
    }
    __syncthreads();
    // exclusive scan of hist in place (becomes cursor); dump tables
    int carry = 0;
    for (int cc = 0; cc < NBUK; cc += 256) {
        int i = cc + tid;
        int v = (i < NBUK) ? hist[i] : 0;
        int incl = wave_incl_scan(v, lane);
        __syncthreads();                 // all reads of this chunk done; wt reusable
        if (lane == 63) wt[wid] = incl;
        __syncthreads();
        int woff = 0;
        #pragma unroll
        for (int w = 0; w < 4; ++w) if (w < wid) woff += wt[w];
        int tot = wt[0] + wt[1] + wt[2] + wt[3];
        int excl = carry + woff + incl - v;
        if (i < NBUK) {
            counts[(size_t)blk * NBUK + i]   = v;
            runstart[(size_t)blk * NBUK + i] = excl;
            hist[i] = excl;              // cursor for pass 2
        }
        carry += tot;
        __syncthreads();
    }
    // pass 2: scatter into private chunk region (single-block writer -> ~1x writeback)
    for (int j = tid; j < cnt; j += 256) {
        int t = base + j;
        int view = t / N_EDGES;
        int i = t - view * N_EDGES;
        const int* rp = (view == 0) ? r0 : (view == 1) ? r1 : r2;
        const int* cp = (view == 0) ? c0 : (view == 1) ? c1 : c2;
        const float* vp = (view == 0) ? v0 : (view == 1) ? v1 : v2;
        int grow = view * N_NODES + rp[i];
        int b = grow >> 7;
        int p = atomicAdd(&hist[b], 1);
        uint2 e;
        e.x = ((unsigned int)(grow & 127) << 16) | (unsigned int)cp[i];  // col < 65536
        e.y = __float_as_uint(vp[i]);
        chunkout[(size_t)blk * CHK + p] = e;
    }
}

// ---------------- phase S1: per-bucket scan of counts over blocks ----------------

__global__ __launch_bounds__(256) void s1_kernel(
    const int* __restrict__ counts, int* __restrict__ offs, int* __restrict__ bsum)
{
    __shared__ int wt[4];
    int b = blockIdx.x, tid = threadIdx.x;
    int lane = tid & 63, wid = tid >> 6;
    int carry = 0;
    for (int cc = 0; cc < NBLK; cc += 256) {
        int i = cc + tid;
        int v = (i < NBLK) ? counts[(size_t)i * NBUK + b] : 0;
        int incl = wave_incl_scan(v, lane);
        __syncthreads();
        if (lane == 63) wt[wid] = incl;
        __syncthreads();
        int woff = 0;
        #pragma unroll
        for (int w = 0; w < 4; ++w) if (w < wid) woff += wt[w];
        int tot = wt[0] + wt[1] + wt[2] + wt[3];
        if (i < NBLK) offs[(size_t)b * (NBLK + 1) + i] = carry + woff + incl - v;
        carry += tot;
        __syncthreads();
    }
    if (tid == 0) {
        offs[(size_t)b * (NBLK + 1) + NBLK] = carry;
        bsum[b] = carry;
    }
}

// ---------------- phase S2: scan bucket sums -> bucket bases ----------------

__global__ __launch_bounds__(256) void s2_kernel(
    const int* __restrict__ bsum, int* __restrict__ bucketbase, int* __restrict__ row_ptr)
{
    __shared__ int wt[4];
    int tid = threadIdx.x;
    int lane = tid & 63, wid = tid >> 6;
    int carry = 0;
    for (int cc = 0; cc < NBUK; cc += 256) {
        int i = cc + tid;
        int v = (i < NBUK) ? bsum[i] : 0;
        int incl = wave_incl_scan(v, lane);
        __syncthreads();
        if (lane == 63) wt[wid] = incl;
        __syncthreads();
        int woff = 0;
        #pragma unroll
        for (int w = 0; w < 4; ++w) if (w < wid) woff += wt[w];
        int tot = wt[0] + wt[1] + wt[2] + wt[3];
        if (i < NBUK) bucketbase[i] = carry + woff + incl - v;
        carry += tot;
        __syncthreads();
    }
    if (tid == 0) {
        bucketbase[NBUK] = carry;
        row_ptr[N3] = carry;
    }
}

// ---------------- phase B: per-bucket gather + row sort + row_ptr ----------------

__global__ __launch_bounds__(256) void binB_kernel(
    const uint2* __restrict__ chunkout, const int* __restrict__ offs,
    const int* __restrict__ runstart, const int* __restrict__ bucketbase,
    int* __restrict__ row_ptr, uint2* __restrict__ cv)
{
    __shared__ int so[NBLK + 1];
    __shared__ int srs[NBLK];
    __shared__ int rh[128];
    __shared__ int wt2[2];
    __shared__ uint2 buf[BUFCAP];
    int b = blockIdx.x, tid = threadIdx.x;
    for (int i = tid; i <= NBLK; i += 256) so[i] = offs[(size_t)b * (NBLK + 1) + i];
    for (int i = tid; i < NBLK; i += 256) srs[i] = runstart[(size_t)i * NBUK + b];
    if (tid < 128) rh[tid] = 0;
    int base = bucketbase[b];
    __syncthreads();
    int cntb = so[NBLK];
    if (cntb > BUFCAP) cntb = BUFCAP;  // statistically impossible; guards LDS OOB
    // gather runs into LDS + row histogram
    for (int i = tid; i < cntb; i += 256) {
        int lo = 0, hi = NBLK;
        while (hi - lo > 1) { int m = (lo + hi) >> 1; if (so[m] <= i) lo = m; else hi = m; }
        uint2 e = chunkout[(size_t)lo * CHK + srs[lo] + (i - so[lo])];
        buf[i] = e;
        atomicAdd(&rh[e.x >> 16], 1);
    }
    __syncthreads();
    // exclusive scan of 128 row counts; write row_ptr
    int rows_in = min(128, N3 - b * 128);
    int v = 0, incl = 0;
    if (tid < 128) {
        v = rh[tid];
        int lane = tid & 63;
        incl = wave_incl_scan(v, lane);
        if (lane == 63) wt2[tid >> 6] = incl;
    }
    __syncthreads();
    int excl = 0;
    if (tid < 128) {
        int woff = (tid >= 64) ? wt2[0] : 0;
        excl = woff + incl - v;
        if (tid < rows_in) row_ptr[b * 128 + tid] = base + excl;
    }
    __syncthreads();
    if (tid < 128) rh[tid] = excl;     // row cursor
    __syncthreads();
    // scatter by row into final cv (private contiguous bucket region)
    for (int i = tid; i < cntb; i += 256) {
        uint2 e = buf[i];
        int lr = e.x >> 16;
        int p = atomicAdd(&rh[lr], 1);
        uint2 o;
        o.x = e.x & 0xFFFFu;
        o.y = e.y;
        cv[(size_t)base + p] = o;
    }
}

// ---------------- weight convert: w1[din][128] fp32 -> w1t[128][dinp] bf16 ----------------

__global__ void wconv_kernel(const float* __restrict__ w, unsigned short* __restrict__ wt,
                             int din, int dinp) {
    int t = blockIdx.x * 256 + threadIdx.x;
    if (t >= 128 * dinp) return;
    int n = t / dinp, k = t - n * dinp;
    float f = (k < din) ? w[(size_t)k * 128 + n] : 0.f;
    wt[(size_t)n * dinp + k] = f2bf(f);
}

// ---------------- GEMM1: xw[N][128] (bf16) = x[N][din] @ w1 (bf16 MFMA) ----------------
// 64x128 tile, 4 waves (each 64 rows x 32 cols), BK=64, register-prefetch pipeline.

#define SAW 72  // LDS row stride (shorts): 144B = 9*16B -> 16B aligned, <=2-way bank alias

__global__ __launch_bounds__(256) void gemm1_kernel(
    const float* __restrict__ x, const unsigned short* __restrict__ w1t,
    unsigned short* __restrict__ xw, int Nn, int din, int dinp)
{
    __shared__ unsigned short As[64 * SAW];
    __shared__ unsigned short Bs[128 * SAW];
    int tid = threadIdx.x;
    int lane = tid & 63, wid = tid >> 6;
    int row0 = blockIdx.x * 64;
    int numK = dinp >> 6;

    int ar = tid >> 4;         // 0..15
    int ak = (tid & 15) * 4;   // 0..60
    float4 apre[4];
    uint4  bpre[4];

    auto loadA = [&](int k0) {
        #pragma unroll
        for (int p = 0; p < 4; ++p) {
            int r = p * 16 + ar;
            int gr = row0 + r;
            int k = k0 + ak;
            float4 v = make_float4(0.f, 0.f, 0.f, 0.f);
            if (gr < Nn) {
                if (k + 4 <= din) {
                    v = *(const float4*)(x + (size_t)gr * din + k);
                } else {
                    float e0 = (k + 0 < din) ? x[(size_t)gr * din + k + 0] : 0.f;
                    float e1 = (k + 1 < din) ? x[(size_t)gr * din + k + 1] : 0.f;
                    float e2 = (k + 2 < din) ? x[(size_t)gr * din + k + 2] : 0.f;
                    float e3 = (k + 3 < din) ? x[(size_t)gr * din + k + 3] : 0.f;
                    v = make_float4(e0, e1, e2, e3);
                }
            }
            apre[p] = v;
        }
    };
    auto loadB = [&](int k0) {
        #pragma unroll
        for (int p = 0; p < 4; ++p) {
            int idx = p * 256 + tid;
            int n = idx >> 3, q = idx & 7;
            bpre[p] = *(const uint4*)(w1t + (size_t)n * dinp + k0 + q * 8);
        }
    };
    auto storeLDS = [&]() {
        #pragma unroll
        for (int p = 0; p < 4; ++p) {
            int r = p * 16 + ar;
            ushort4 bb;
            bb.x = f2bf(apre[p].x); bb.y = f2bf(apre[p].y);
            bb.z = f2bf(apre[p].z); bb.w = f2bf(apre[p].w);
            *(ushort4*)(&As[r * SAW + ak]) = bb;
        }
        #pragma unroll
        for (int p = 0; p < 4; ++p) {
            int idx = p * 256 + tid;
            int n = idx >> 3, q = idx & 7;
            *(uint4*)(&Bs[n * SAW + q * 8]) = bpre[p];
        }
    };

    loadA(0); loadB(0);
    storeLDS();

    int kq = (lane >> 4) * 8;
    int sub = lane & 15;
    f32x4 acc[4][2] = {};
    for (int kt = 0;;) {
        __syncthreads();
        bool more = (kt + 1 < numK);
        if (more) { loadA((kt + 1) << 6); loadB((kt + 1) << 6); }
        #pragma unroll
        for (int kh = 0; kh < 2; ++kh) {
            bf16x8 af[4], bfr[2];
            #pragma unroll
            for (int mt = 0; mt < 4; ++mt)
                af[mt] = *(const bf16x8*)(&As[(mt * 16 + sub) * SAW + kh * 32 + kq]);
            #pragma unroll
            for (int nt = 0; nt < 2; ++nt)
                bfr[nt] = *(const bf16x8*)(&Bs[(wid * 32 + nt * 16 + sub) * SAW + kh * 32 + kq]);
            #pragma unroll
            for (int mt = 0; mt < 4; ++mt)
                #pragma unroll
                for (int nt = 0; nt < 2; ++nt)
                    acc[mt][nt] = __builtin_amdgcn_mfma_f32_16x16x32_bf16(af[mt], bfr[nt], acc[mt][nt], 0, 0, 0);
        }
        if (!more) break;
        __syncthreads();
        storeLDS();
        ++kt;
    }

    #pragma unroll
    for (int mt = 0; mt < 4; ++mt) {
        #pragma unroll
        for (int nt = 0; nt < 2; ++nt) {
            int col = wid * 32 + nt * 16 + (lane & 15);
            #pragma unroll
            for (int r = 0; r < 4; ++r) {
                int row = row0 + mt * 16 + (lane >> 4) * 4 + r;
                if (row < Nn) xw[(size_t)row * 128 + col] = f2bf(acc[mt][nt][r]);
            }
        }
    }
}

// ---------------- SpMM F=128 (bf16 src), bias+relu, bf16 dst ----------------

__global__ __launch_bounds__(256) void spmm128_kernel(
    const unsigned short* __restrict__ src, const int* __restrict__ row_ptr,
    const float2* __restrict__ cv, const float* __restrict__ bias,
    unsigned short* __restrict__ dst)
{
    const unsigned int* srcu = (const unsigned int*)src;
    int lane = threadIdx.x & 63;
    int r = blockIdx.x * 4 + (threadIdx.x >> 6);
    int s = row_ptr[r], e = row_ptr[r + 1];
    float a0 = 0.f, a1 = 0.f, b0 = 0.f, b1 = 0.f;
    int j = s;
    for (; j + 8 <= e; j += 8) {
        float2 p0 = cv[j], p1 = cv[j + 1], p2 = cv[j + 2], p3 = cv[j + 3];
        float2 p4 = cv[j + 4], p5 = cv[j + 5], p6 = cv[j + 6], p7 = cv[j + 7];
        unsigned int t0 = srcu[(size_t)__float_as_uint(p0.x) * 64 + lane];
        unsigned int t1 = srcu[(size_t)__float_as_uint(p1.x) * 64 + lane];
        unsigned int t2 = srcu[(size_t)__float_as_uint(p2.x) * 64 + lane];
        unsigned int t3 = srcu[(size_t)__float_as_uint(p3.x) * 64 + lane];
        unsigned int t4 = srcu[(size_t)__float_as_uint(p4.x) * 64 + lane];
        unsigned int t5 = srcu[(size_t)__float_as_uint(p5.x) * 64 + lane];
        unsigned int t6 = srcu[(size_t)__float_as_uint(p6.x) * 64 + lane];
        unsigned int t7 = srcu[(size_t)__float_as_uint(p7.x) * 64 + lane];
        a0 += p0.y * bflo(t0); a1 += p0.y * bfhi(t0);
        b0 += p1.y * bflo(t1); b1 += p1.y * bfhi(t1);
        a0 += p2.y * bflo(t2); a1 += p2.y * bfhi(t2);
        b0 += p3.y * bflo(t3); b1 += p3.y * bfhi(t3);
        a0 += p4.y * bflo(t4); a1 += p4.y * bfhi(t4);
        b0 += p5.y * bflo(t5); b1 += p5.y * bfhi(t5);
        a0 += p6.y * bflo(t6); a1 += p6.y * bfhi(t6);
        b0 += p7.y * bflo(t7); b1 += p7.y * bfhi(t7);
    }
    for (; j < e; ++j) {
        float2 p = cv[j];
        unsigned int t = srcu[(size_t)__float_as_uint(p.x) * 64 + lane];
        a0 += p.y * bflo(t); a1 += p.y * bfhi(t);
    }
    a0 += b0 + bias[lane * 2];
    a1 += b1 + bias[lane * 2 + 1];
    a0 = fmaxf(a0, 0.f); a1 = fmaxf(a1, 0.f);
    unsigned int o = (unsigned int)f2bf(a0) | ((unsigned int)f2bf(a1) << 16);
    ((unsigned int*)dst)[(size_t)r * 64 + lane] = o;
}

// ---------------- SpMM F=64 (bf16 src), +bias, fp32 dst ----------------

__global__ __launch_bounds__(256) void spmm64_kernel(
    const unsigned short* __restrict__ src, const int* __restrict__ row_ptr,
    const float2* __restrict__ cv, const float* __restrict__ bias,
    float* __restrict__ dst)
{
    int lane = threadIdx.x & 63;
    int r = blockIdx.x * 4 + (threadIdx.x >> 6);
    int s = row_ptr[r], e = row_ptr[r + 1];
    float a0 = 0.f, b0 = 0.f;
    int j = s;
    for (; j + 8 <= e; j += 8) {
        float2 p0 = cv[j], p1 = cv[j + 1], p2 = cv[j + 2], p3 = cv[j + 3];
        float2 p4 = cv[j + 4], p5 = cv[j + 5], p6 = cv[j + 6], p7 = cv[j + 7];
        float f0 = __uint_as_float((unsigned int)src[(size_t)__float_as_uint(p0.x) * 64 + lane] << 16);
        float f1 = __uint_as_float((unsigned int)src[(size_t)__float_as_uint(p1.x) * 64 + lane] << 16);
        float f2 = __uint_as_float((unsigned int)src[(size_t)__float_as_uint(p2.x) * 64 + lane] << 16);
        float f3 = __uint_as_float((unsigned int)src[(size_t)__float_as_uint(p3.x) * 64 + lane] << 16);
        float f4 = __uint_as_float((unsigned int)src[(size_t)__float_as_uint(p4.x) * 64 + lane] << 16);
        float f5 = __uint_as_float((unsigned int)src[(size_t)__float_as_uint(p5.x) * 64 + lane] << 16);
        float f6 = __uint_as_float((unsigned int)src[(size_t)__float_as_uint(p6.x) * 64 + lane] << 16);
        float f7 = __uint_as_float((unsigned int)src[(size_t)__float_as_uint(p7.x) * 64 + lane] << 16);
        a0 += p0.y * f0; b0 += p1.y * f1;
        a0 += p2.y * f2; b0 += p3.y * f3;
        a0 += p4.y * f4; b0 += p5.y * f5;
        a0 += p6.y * f6; b0 += p7.y * f7;
    }
    for (; j < e; ++j) {
        float2 p = cv[j];
        float f = __uint_as_float((unsigned int)src[(size_t)__float_as_uint(p.x) * 64 + lane] << 16);
        a0 += p.y * f;
    }
    dst[(size_t)r * 64 + lane] = a0 + b0 + bias[lane];
}

// ---------------- GEMM2: hw[N][64] (bf16) = h[N][128] (bf16) @ w2[128][64] (fp32 LDS) ----

__global__ __launch_bounds__(256) void gemm2_kernel(
    const unsigned short* __restrict__ h, const float* __restrict__ w2,
    unsigned short* __restrict__ hw)
{
    __shared__ float w2s[128 * 64];
    int tid = threadIdx.x;
    for (int i = tid; i < 128 * 64; i += 256) w2s[i] = w2[i];
    __syncthreads();
    int n = tid & 63, g = tid >> 6;
    int r0 = blockIdx.x * 16 + g * 4;
    const unsigned int* h0 = (const unsigned int*)(h + (size_t)r0 * 128);
    float a0 = 0.f, a1 = 0.f, a2 = 0.f, a3 = 0.f;
    #pragma unroll 4
    for (int k2 = 0; k2 < 64; ++k2) {
        unsigned int t0 = h0[k2], t1 = h0[64 + k2], t2 = h0[128 + k2], t3 = h0[192 + k2];
        float w0 = w2s[(2 * k2) * 64 + n];
        float w1 = w2s[(2 * k2 + 1) * 64 + n];
        a0 += bflo(t0) * w0 + bfhi(t0) * w1;
        a1 += bflo(t1) * w0 + bfhi(t1) * w1;
        a2 += bflo(t2) * w0 + bfhi(t2) * w1;
        a3 += bflo(t3) * w0 + bfhi(t3) * w1;
    }
    hw[(size_t)(r0 + 0) * 64 + n] = f2bf(a0);
    hw[(size_t)(r0 + 1) * 64 + n] = f2bf(a1);
    hw[(size_t)(r0 + 2) * 64 + n] = f2bf(a2);
    hw[(size_t)(r0 + 3) * 64 + n] = f2bf(a3);
}

// ---------------- fusion: z_fused = relu(concat(z0,z1,z2) @ fw + fb) ----------------

__global__ __launch_bounds__(256) void fusion_kernel(
    const float* __restrict__ z, const float* __restrict__ fw,
    const float* __restrict__ fb, float* __restrict__ zf)
{
    __shared__ float ws_[192 * 64];  // 48 KB
    int tid = threadIdx.x;
    for (int i = tid; i < 192 * 64; i += 256) ws_[i] = fw[i];
    __syncthreads();
    int n = tid & 63, g = tid >> 6;
    int r0 = blockIdx.x * 16 + g * 4;
    float a0 = 0.f, a1 = 0.f, a2 = 0.f, a3 = 0.f;
    #pragma unroll
    for (int v = 0; v < 3; ++v) {
        const float* zv = z + (size_t)v * N_NODES * 64;
        const float* z0 = zv + (size_t)(r0 + 0) * 64;
        const float* z1 = zv + (size_t)(r0 + 1) * 64;
        const float* z2 = zv + (size_t)(r0 + 2) * 64;
        const float* z3 = zv + (size_t)(r0 + 3) * 64;
        #pragma unroll 4
        for (int k = 0; k < 64; ++k) {
            float w = ws_[(v * 64 + k) * 64 + n];
            a0 += z0[k] * w; a1 += z1[k] * w; a2 += z2[k] * w; a3 += z3[k] * w;
        }
    }
    float b = fb[n];
    zf[(size_t)(r0 + 0) * 64 + n] = fmaxf(a0 + b, 0.f);
    zf[(size_t)(r0 + 1) * 64 + n] = fmaxf(a1 + b, 0.f);
    zf[(size_t)(r0 + 2) * 64 + n] = fmaxf(a2 + b, 0.f);
    zf[(size_t)(r0 + 3) * 64 + n] = fmaxf(a3 + b, 0.f);
}

// ---------------- q: Student-t soft assignment ----------------

__global__ __launch_bounds__(256) void q_kernel(
    const float* __restrict__ zf, const float* __restrict__ cluster, float* __restrict__ q)
{
    int lane = threadIdx.x & 63;
    int r = blockIdx.x * 4 + (threadIdx.x >> 6);
    float zl = zf[(size_t)r * 64 + lane];
    float d2[NCLU];
    #pragma unroll
    for (int k = 0; k < NCLU; ++k) {
        float d = zl - cluster[k * 64 + lane];
        float s = d * d;
        #pragma unroll
        for (int m = 32; m; m >>= 1) s += __shfl_xor(s, m, 64);
        d2[k] = s;
    }
    float S = 0.f;
    #pragma unroll
    for (int k = 0; k < NCLU; ++k) S += 1.f / (1.f + d2[k]);
    float myq = 0.f;
    #pragma unroll
    for (int k = 0; k < NCLU; ++k)
        if (lane == k) myq = 1.f / (1.f + d2[k]);
    if (lane < NCLU) q[(size_t)r * NCLU + lane] = myq / S;
}

// ---------------- launch ----------------

extern "C" void kernel_launch(void* const* d_in, const int* in_sizes, int n_in,
                              void* d_out, int out_size, void* d_ws, size_t ws_size,
                              hipStream_t stream)
{
    const int N = N_NODES;
    static const int dins[3] = {1000, 800, 600};
    float* out = (float*)d_out;
    char* base = (char*)d_ws;

    // ---- workspace layout with aliasing (ws ~54MB available) ----
    // [0]              cv:        E3*8   = 19,200,000
    // [r1]  chunkout (E3-pad *8 = 19,202,048)  ALIAS  h (12.8M) + hw (6.4M)
    // [r2]  tables (~8.3M)                     ALIAS  xw (12.8M)
    // [w1t] 128*1024*2, [row_ptr] (N3+1)*4
    size_t oCv  = 0;
    size_t oR1  = (oCv + (size_t)E3 * 8 + 255) & ~(size_t)255;
    size_t szR1 = (size_t)NBLK * CHK * 8;                       // 19,202,048 >= h+hw
    size_t oR2  = (oR1 + szR1 + 255) & ~(size_t)255;
    size_t szR2 = (size_t)N * 128 * 2;                          // 12.8M >= tables (8.3M)
    size_t oW1t = (oR2 + szR2 + 255) & ~(size_t)255;
    size_t oRp  = (oW1t + (size_t)128 * 1024 * 2 + 255) & ~(size_t)255;

    uint2* cv        = (uint2*)(base + oCv);
    uint2* chunkout  = (uint2*)(base + oR1);
    unsigned short* h  = (unsigned short*)(base + oR1);
    unsigned short* hw = (unsigned short*)(base + oR1 + (size_t)N * 128 * 2);
    unsigned short* xw = (unsigned short*)(base + oR2);
    int* runstart   = (int*)(base + oR2);
    int* counts     = (int*)(base + oR2 + (size_t)NBLK * NBUK * 4);
    int* offs       = (int*)(base + oR2 + (size_t)NBLK * NBUK * 8);
    int* bsum       = (int*)(base + oR2 + (size_t)NBLK * NBUK * 8 + (size_t)NBUK * (NBLK + 1) * 4);
    int* bucketbase = bsum + NBUK + 4;
    unsigned short* w1t = (unsigned short*)(base + oW1t);
    int* row_ptr    = (int*)(base + oRp);

    const int* rows0 = (const int*)d_in[1];
    const int* cols0 = (const int*)d_in[2];
    const float* vals0 = (const float*)d_in[3];
    const int* rows1 = (const int*)d_in[9];
    const int* cols1 = (const int*)d_in[10];
    const float* vals1 = (const float*)d_in[11];
    const int* rows2 = (const int*)d_in[17];
    const int* cols2 = (const int*)d_in[18];
    const float* vals2 = (const float*)d_in[19];

    // ---- CSR build: two-phase stable bucket sort, block-private writes only ----
    binA_kernel<<<NBLK, 256, 0, stream>>>(rows0, cols0, vals0, rows1, cols1, vals1,
                                          rows2, cols2, vals2, runstart, counts, chunkout);
    s1_kernel<<<NBUK, 256, 0, stream>>>(counts, offs, bsum);
    s2_kernel<<<1, 256, 0, stream>>>(bsum, bucketbase, row_ptr);
    binB_kernel<<<NBUK, 256, 0, stream>>>(chunkout, offs, runstart, bucketbase, row_ptr, cv);

    for (int v = 0; v < 3; ++v) {
        const float* x    = (const float*)d_in[8 * v + 0];
        const float* w1   = (const float*)d_in[8 * v + 4];
        const float* b1   = (const float*)d_in[8 * v + 5];
        const float* w2   = (const float*)d_in[8 * v + 6];
        const float* b2   = (const float*)d_in[8 * v + 7];
        int din = dins[v], dinp = (din + 63) & ~63;

        wconv_kernel<<<(128 * dinp + 255) / 256, 256, 0, stream>>>(w1, w1t, din, dinp);
        gemm1_kernel<<<(N + 63) / 64, 256, 0, stream>>>(x, w1t, xw, N, din, dinp);
        spmm128_kernel<<<N / 4, 256, 0, stream>>>(xw, row_ptr + v * N, (const float2*)cv, b1, h);
        gemm2_kernel<<<N / 16, 256, 0, stream>>>(h, w2, hw);
        spmm64_kernel<<<N / 4, 256, 0, stream>>>(hw, row_ptr + v * N, (const float2*)cv, b2,
                                                 out + (size_t)v * N * 64);
    }
    const float* fw = (const float*)d_in[24];
    const float* fb = (const float*)d_in[25];
    const float* cl = (const float*)d_in[26];
    fusion_kernel<<<N / 16, 256, 0, stream>>>(out, fw, fb, out + (size_t)3 * N * 64);
    q_kernel<<<N / 4, 256, 0, stream>>>(out + (size_t)3 * N * 64, cl, out + (size_t)4 * N * 64);
}